// Round 10
// baseline (76.326 us; speedup 1.0000x reference)
//
#include <hip/hip_runtime.h>

// CRF log-likelihood, B=128, T=2048, K=96 on gfx950.
//
// Chunked-parallel forward algorithm (verified R3/R4): logZ telescopes into
// per-chunk Phi differences; exp(trans) contracts normalized alpha at
// Birkhoff rate ~0.37/step, so chunks warm up from a fabricated init
// WARM=16 steps early. Chunk contribution = Phi(end) - Phi(after-warmup).
//
// Round 10: R9 minus the bug that killed rounds 6-9: with CLEN=8 < WARM=16,
// s_init = c*CLEN - WARM went NEGATIVE for small c; (size_t)s*K then turned
// it into a wild 64-bit offset -> garbage reads (R6-R8 NaN: offset landed in
// other ws arrays) or a fault (R9 core dump: raw input pointer). Fix:
// s_init = max(0, c*CLEN - WARM). Clipped chunks start from the TRUE t=0
// init (alpha_0 = exp(emit_0), exact), so accuracy only improves.
// Everything else is R4's verified kernels with CHUNKS=256 (2048 one-wave
// blocks = 8/CU, 24-step chains instead of 48).

constexpr int K      = 96;
constexpr int NB     = 16;   // batches per wave (MFMA N dim)
constexpr int CHUNKS = 256;
constexpr int CLEN   = 8;    // accumulated steps per chunk
constexpr int WARM   = 16;   // warm-up steps (clipped at t=0)
constexpr int B      = 128;

typedef __attribute__((ext_vector_type(8))) short bf16x8;
typedef __attribute__((ext_vector_type(4))) float f32x4;

__device__ __forceinline__ unsigned short f2bf(float f) {
  unsigned int b = __float_as_uint(f);
  return (unsigned short)((b + 0x7fff + ((b >> 16) & 1)) >> 16);  // RNE
}
__device__ __forceinline__ float bf2f(unsigned short h) {
  return __uint_as_float(((unsigned int)h) << 16);
}
__device__ __forceinline__ unsigned int cvt_pk_bf16(float lo, float hi) {
  unsigned int r;
  asm volatile("v_cvt_pk_bf16_f32 %0, %1, %2" : "=v"(r) : "v"(lo), "v"(hi));
  return r;
}
__device__ __forceinline__ float lane_bcast(int addr4, float v) {
  return __int_as_float(__builtin_amdgcn_ds_bpermute(addr4, __float_as_int(v)));
}

__global__ __launch_bounds__(64, 1) void crf_fwd_chunk(
    const float* __restrict__ inp,    // [B,T,K]
    const int*   __restrict__ tags,   // [B,T]
    const int*   __restrict__ mask,   // [B,T]
    const float* __restrict__ trans,  // [K,K]
    float* __restrict__ pden,         // [CHUNKS][B]
    float* __restrict__ pnum,         // [CHUNKS][B]
    float* __restrict__ pcnt,         // [CHUNKS][B]
    int T)
{
  const int l  = threadIdx.x;
  const int bl = l & 15;     // batch-in-group (= MFMA col)
  const int hi = l >> 4;
  const int g  = blockIdx.x;
  const int c  = blockIdx.y;
  const int b  = g * NB + bl;
  const int bcast = bl * 4;

  // R6-R9 bug fixed here: clamp at 0 (CLEN < WARM made this negative).
  const int s_init = max(0, c * CLEN - WARM);
  const int s_A    = c * CLEN;
  const int s_end  = min(c * CLEN + CLEN, T - 1);

  __shared__ unsigned short Xs[NB][104];   // bf16 state, stride 104 shorts

  // A fragments: A[row=j][k=i] = exp(trans[i][j]); row=lane&15, k=(lane>>4)*8+e
  bf16x8 A[6][3];
  #pragma unroll
  for (int jt = 0; jt < 6; ++jt) {
    #pragma unroll
    for (int kf = 0; kf < 3; ++kf) {
      const int j = jt * 16 + bl;
      #pragma unroll
      for (int e = 0; e < 8; ++e) {
        const int i = kf * 32 + hi * 8 + e;
        A[jt][kf][e] = (short)f2bf(__expf(trans[i * K + j]));
      }
    }
  }

  const float* ib  = inp  + (size_t)b * T * K;
  const int*   mb  = mask + (size_t)b * T;
  const int*   tgb = tags + (size_t)b * T;

  // ---- init at s_init: x = exp(emit - emit[0]) (exact for s_init==0) ----
  {
    const float* i0 = ib + (size_t)s_init * K;
    float4 e0[6];
    #pragma unroll
    for (int jt = 0; jt < 6; ++jt) {
      float4 v = *(const float4*)(i0 + jt * 16 + hi * 4);
      v.x = __expf(v.x); v.y = __expf(v.y); v.z = __expf(v.z); v.w = __expf(v.w);
      e0[jt] = v;
    }
    const float r0  = lane_bcast(bcast, e0[0].x);
    const float inv = 1.0f / r0;
    #pragma unroll
    for (int jt = 0; jt < 6; ++jt) {
      uint2 p;
      p.x = cvt_pk_bf16(e0[jt].x * inv, e0[jt].y * inv);
      p.y = cvt_pk_bf16(e0[jt].z * inv, e0[jt].w * inv);
      *(uint2*)&Xs[bl][jt * 16 + hi * 4] = p;
    }
  }
  double Mref = (double)ib[(size_t)s_init * K];

  bf16x8 Bf[3];
  #pragma unroll
  for (int kf = 0; kf < 3; ++kf)
    Bf[kf] = *(const bf16x8*)&Xs[bl][kf * 32 + hi * 8];

  // depth-3 prefetch buffers (named; all indexing compile-time)
  float4 e0b[6], e1b[6], e2b[6];
  int    m0 = 0, m1 = 0, m2 = 0;

  auto load = [&](int s, float4 (&e)[6], int& m) {
    #pragma unroll
    for (int jt = 0; jt < 6; ++jt)
      e[jt] = *(const float4*)(ib + (size_t)s * K + jt * 16 + hi * 4);
    m = mb[s];
  };

  auto step = [&](int s, float4 (&ebuf)[6], int& msl) {
    f32x4 acc[6];
    #pragma unroll
    for (int jt = 0; jt < 6; ++jt) {
      f32x4 a = {0.f, 0.f, 0.f, 0.f};
      a = __builtin_amdgcn_mfma_f32_16x16x32_bf16(A[jt][0], Bf[0], a, 0, 0, 0);
      a = __builtin_amdgcn_mfma_f32_16x16x32_bf16(A[jt][1], Bf[1], a, 0, 0, 0);
      a = __builtin_amdgcn_mfma_f32_16x16x32_bf16(A[jt][2], Bf[2], a, 0, 0, 0);
      acc[jt] = a;
    }
    const float r   = lane_bcast(bcast, acc[0][0]);   // C[0][b]
    const float inv = 1.0f / r;
    const bool  mm  = msl != 0;
    if (mm) Mref += (double)__logf(r);

    float xv[6][4];
    #pragma unroll
    for (int jt = 0; jt < 6; ++jt) {
      float4 e4 = ebuf[jt];
      e4.x = __expf(e4.x); e4.y = __expf(e4.y);
      e4.z = __expf(e4.z); e4.w = __expf(e4.w);
      xv[jt][0] = acc[jt][0] * (e4.x * inv);
      xv[jt][1] = acc[jt][1] * (e4.y * inv);
      xv[jt][2] = acc[jt][2] * (e4.z * inv);
      xv[jt][3] = acc[jt][3] * (e4.w * inv);
    }

    if (s + 3 <= s_end) load(s + 3, ebuf, msl);   // refill own buffer

    if (mm) {   // masked steps keep old x
      #pragma unroll
      for (int jt = 0; jt < 6; ++jt) {
        uint2 p;
        p.x = cvt_pk_bf16(xv[jt][0], xv[jt][1]);
        p.y = cvt_pk_bf16(xv[jt][2], xv[jt][3]);
        *(uint2*)&Xs[bl][jt * 16 + hi * 4] = p;
      }
    }
    #pragma unroll
    for (int kf = 0; kf < 3; ++kf)
      Bf[kf] = *(const bf16x8*)&Xs[bl][kf * 32 + hi * 8];
  };

  auto phi = [&]() -> double {
    float sum = 0.f;
    #pragma unroll
    for (int u = 0; u < 24; ++u) sum += bf2f(Xs[bl][hi * 24 + u]);
    sum += __shfl_xor(sum, 16);
    sum += __shfl_xor(sum, 32);
    return Mref + (double)__logf(sum);
  };

  // prologue: fill 3 buffers (every chunk has >= 8 steps)
  load(s_init + 1, e0b, m0);
  load(s_init + 2, e1b, m1);
  load(s_init + 3, e2b, m2);

  double phiA = 0.0;   // c == 0: Phi before chunk is 0 by construction
  int s = s_init + 1;
  for (; s + 2 <= s_end; s += 3) {
    step(s,     e0b, m0); if (s     == s_A) phiA = phi();
    step(s + 1, e1b, m1); if (s + 1 == s_A) phiA = phi();
    step(s + 2, e2b, m2); if (s + 2 == s_A) phiA = phi();
  }
  // tails (c==0: 8=2*3+2; c==1: 16=5*3+1; s_A is never in a tail position)
  if (s <= s_end) { step(s, e0b, m0); ++s; }
  if (s <= s_end) { step(s, e1b, m1); ++s; }
  const double phiB = phi();

  if (hi == 0) pden[c * B + b] = (float)(phiB - phiA);

  // ---- fused numerator: gold-path terms for t in [c*CLEN, c*CLEN+CLEN) ----
  const int t0 = c * CLEN;
  float nacc = 0.f, mcnt = 0.f;
  #pragma unroll
  for (int k = 0; k < CLEN / 4; ++k) {
    const int t  = t0 + 4 * k + hi;
    const int mt = mb[t];
    mcnt += (float)mt;
    if (t < T - 1) {
      const int tg  = tgb[t];
      const int tg1 = tgb[t + 1];
      nacc = fmaf(trans[tg * K + tg1], (float)mb[t + 1], nacc);
      nacc = fmaf(ib[(size_t)t * K + tg], (float)mt, nacc);
    }
  }
  nacc += __shfl_xor(nacc, 16); nacc += __shfl_xor(nacc, 32);
  mcnt += __shfl_xor(mcnt, 16); mcnt += __shfl_xor(mcnt, 32);
  if (hi == 0) {
    pnum[c * B + b] = nacc;
    pcnt[c * B + b] = mcnt;
  }
}

// ---------------- final reduce: last-tag gather + sum ----------------
__global__ __launch_bounds__(128) void crf_reduce(
    const float* __restrict__ inp, const int* __restrict__ tags,
    const int* __restrict__ mask,
    const float* __restrict__ pden, const float* __restrict__ pnum,
    const float* __restrict__ pcnt, float* __restrict__ out, int T)
{
  const int b = threadIdx.x;   // 128 = B
  float den = 0.f, num = 0.f, cnt = 0.f;
  for (int c = 0; c < CHUNKS; ++c) {
    den += pden[c * B + b];
    num += pnum[c * B + b];
    cnt += pcnt[c * B + b];
  }
  const int last_idx = (int)cnt - 1;
  float last_sc = 0.f;
  if (last_idx >= 0) {
    const int lt = tags[(size_t)b * T + last_idx];
    last_sc = inp[((size_t)b * T + (T - 1)) * K + lt]
            * (float)mask[(size_t)b * T + T - 1];
  }
  __shared__ float red[128];
  red[b] = num + last_sc - den;
  __syncthreads();
  #pragma unroll
  for (int s = 64; s > 0; s >>= 1) {
    if (b < s) red[b] += red[b + s];
    __syncthreads();
  }
  if (b == 0) out[0] = red[0];
}

extern "C" void kernel_launch(void* const* d_in, const int* in_sizes, int n_in,
                              void* d_out, int out_size, void* d_ws, size_t ws_size,
                              hipStream_t stream)
{
  const float* inp   = (const float*)d_in[0];
  const int*   tags  = (const int*)  d_in[1];
  const int*   mask  = (const int*)  d_in[2];
  const float* trans = (const float*)d_in[3];
  float*       out   = (float*)d_out;

  const int BT = in_sizes[1];
  const int T  = BT / B;   // 2048

  float* pden = (float*)d_ws;            // [CHUNKS][B]
  float* pnum = pden + CHUNKS * B;       // [CHUNKS][B]
  float* pcnt = pnum + CHUNKS * B;       // [CHUNKS][B]

  dim3 grid(B / NB, CHUNKS);
  crf_fwd_chunk<<<grid, 64, 0, stream>>>(inp, tags, mask, trans,
                                         pden, pnum, pcnt, T);
  crf_reduce<<<1, 128, 0, stream>>>(inp, tags, mask, pden, pnum, pcnt, out, T);

  (void)n_in; (void)out_size; (void)ws_size;
}

// Round 11
// 74.391 us; speedup vs baseline: 1.0260x; 1.0260x over previous
//
#include <hip/hip_runtime.h>

// CRF log-likelihood, B=128, T=2048, K=96 on gfx950.
//
// Chunked-parallel forward algorithm (verified R3/R4/R10): logZ telescopes
// into per-chunk Phi differences; exp(trans) contracts normalized alpha at
// Birkhoff rate ~0.37/step, so chunks warm up from a (clamped) init WARM=16
// steps early. Chunk contribution = Phi(end) - Phi(after-warmup).
//
// Round 11: R10 passed but VGPR_Count=136 proved the depth-3 "prefetch" was
// sunk to its use site by regalloc (A-frags alone are 72 VGPRs; the 54-VGPR
// buffers were never allocated) -> every step exposed full memory latency
// (tau 3.7us/step at 8 waves/CU). This round restructures the step so the
// refill is (a) issued ~2.7 steps before first use and (b) PINNED with
// sched_barrier(0) so the scheduler cannot sink it: consume ebuf into
// exp()'d registers first, refill ebuf (pinned), then MFMA/recenter/publish.
// Everything else is byte-identical to R10's verified kernels.

constexpr int K      = 96;
constexpr int NB     = 16;   // batches per wave (MFMA N dim)
constexpr int CHUNKS = 256;
constexpr int CLEN   = 8;    // accumulated steps per chunk
constexpr int WARM   = 16;   // warm-up steps (clamped at t=0)
constexpr int B      = 128;

typedef __attribute__((ext_vector_type(8))) short bf16x8;
typedef __attribute__((ext_vector_type(4))) float f32x4;

__device__ __forceinline__ unsigned short f2bf(float f) {
  unsigned int b = __float_as_uint(f);
  return (unsigned short)((b + 0x7fff + ((b >> 16) & 1)) >> 16);  // RNE
}
__device__ __forceinline__ float bf2f(unsigned short h) {
  return __uint_as_float(((unsigned int)h) << 16);
}
__device__ __forceinline__ unsigned int cvt_pk_bf16(float lo, float hi) {
  unsigned int r;
  asm volatile("v_cvt_pk_bf16_f32 %0, %1, %2" : "=v"(r) : "v"(lo), "v"(hi));
  return r;
}
__device__ __forceinline__ float lane_bcast(int addr4, float v) {
  return __int_as_float(__builtin_amdgcn_ds_bpermute(addr4, __float_as_int(v)));
}

__global__ __launch_bounds__(64, 1) void crf_fwd_chunk(
    const float* __restrict__ inp,    // [B,T,K]
    const int*   __restrict__ tags,   // [B,T]
    const int*   __restrict__ mask,   // [B,T]
    const float* __restrict__ trans,  // [K,K]
    float* __restrict__ pden,         // [CHUNKS][B]
    float* __restrict__ pnum,         // [CHUNKS][B]
    float* __restrict__ pcnt,         // [CHUNKS][B]
    int T)
{
  const int l  = threadIdx.x;
  const int bl = l & 15;     // batch-in-group (= MFMA col)
  const int hi = l >> 4;
  const int g  = blockIdx.x;
  const int c  = blockIdx.y;
  const int b  = g * NB + bl;
  const int bcast = bl * 4;

  const int s_init = max(0, c * CLEN - WARM);   // clamp (R10 bug fix)
  const int s_A    = c * CLEN;
  const int s_end  = min(c * CLEN + CLEN, T - 1);

  __shared__ unsigned short Xs[NB][104];   // bf16 state, stride 104 shorts

  // A fragments: A[row=j][k=i] = exp(trans[i][j]); row=lane&15, k=(lane>>4)*8+e
  bf16x8 A[6][3];
  #pragma unroll
  for (int jt = 0; jt < 6; ++jt) {
    #pragma unroll
    for (int kf = 0; kf < 3; ++kf) {
      const int j = jt * 16 + bl;
      #pragma unroll
      for (int e = 0; e < 8; ++e) {
        const int i = kf * 32 + hi * 8 + e;
        A[jt][kf][e] = (short)f2bf(__expf(trans[i * K + j]));
      }
    }
  }

  const float* ib  = inp  + (size_t)b * T * K;
  const int*   mb  = mask + (size_t)b * T;
  const int*   tgb = tags + (size_t)b * T;

  // ---- init at s_init: x = exp(emit - emit[0]) (exact for s_init==0) ----
  {
    const float* i0 = ib + (size_t)s_init * K;
    float4 e0[6];
    #pragma unroll
    for (int jt = 0; jt < 6; ++jt) {
      float4 v = *(const float4*)(i0 + jt * 16 + hi * 4);
      v.x = __expf(v.x); v.y = __expf(v.y); v.z = __expf(v.z); v.w = __expf(v.w);
      e0[jt] = v;
    }
    const float r0  = lane_bcast(bcast, e0[0].x);
    const float inv = 1.0f / r0;
    #pragma unroll
    for (int jt = 0; jt < 6; ++jt) {
      uint2 p;
      p.x = cvt_pk_bf16(e0[jt].x * inv, e0[jt].y * inv);
      p.y = cvt_pk_bf16(e0[jt].z * inv, e0[jt].w * inv);
      *(uint2*)&Xs[bl][jt * 16 + hi * 4] = p;
    }
  }
  double Mref = (double)ib[(size_t)s_init * K];

  bf16x8 Bf[3];
  #pragma unroll
  for (int kf = 0; kf < 3; ++kf)
    Bf[kf] = *(const bf16x8*)&Xs[bl][kf * 32 + hi * 8];

  // depth-3 prefetch buffers (named; all indexing compile-time)
  float4 e0b[6], e1b[6], e2b[6];
  int    m0 = 0, m1 = 0, m2 = 0;

  auto load = [&](int s, float4 (&e)[6], int& m) {
    #pragma unroll
    for (int jt = 0; jt < 6; ++jt)
      e[jt] = *(const float4*)(ib + (size_t)s * K + jt * 16 + hi * 4);
    m = mb[s];
  };

  auto step = [&](int s, float4 (&ebuf)[6], int& msl) {
    // (1) consume the buffer NOW: exp(emissions) into registers
    float4 xe[6];
    #pragma unroll
    for (int jt = 0; jt < 6; ++jt) {
      const float4 e4 = ebuf[jt];
      xe[jt].x = __expf(e4.x); xe[jt].y = __expf(e4.y);
      xe[jt].z = __expf(e4.z); xe[jt].w = __expf(e4.w);
    }
    const bool mm = msl != 0;

    // (2) refill this buffer for step s+3 — pinned so it cannot sink
    if (s + 3 <= s_end) {
      __builtin_amdgcn_sched_barrier(0);
      #pragma unroll
      for (int jt = 0; jt < 6; ++jt)
        ebuf[jt] = *(const float4*)(ib + (size_t)(s + 3) * K + jt * 16 + hi * 4);
      msl = mb[s + 3];
      __builtin_amdgcn_sched_barrier(0);
    }

    // (3) MFMA contraction
    f32x4 acc[6];
    #pragma unroll
    for (int jt = 0; jt < 6; ++jt) {
      f32x4 a = {0.f, 0.f, 0.f, 0.f};
      a = __builtin_amdgcn_mfma_f32_16x16x32_bf16(A[jt][0], Bf[0], a, 0, 0, 0);
      a = __builtin_amdgcn_mfma_f32_16x16x32_bf16(A[jt][1], Bf[1], a, 0, 0, 0);
      a = __builtin_amdgcn_mfma_f32_16x16x32_bf16(A[jt][2], Bf[2], a, 0, 0, 0);
      acc[jt] = a;
    }

    // (4) recenter by r = C[0][b]
    const float r   = lane_bcast(bcast, acc[0][0]);
    const float inv = 1.0f / r;
    if (mm) Mref += (double)__logf(r);

    // (5) new state; masked steps keep old x
    if (mm) {
      #pragma unroll
      for (int jt = 0; jt < 6; ++jt) {
        uint2 p;
        p.x = cvt_pk_bf16(acc[jt][0] * inv * xe[jt].x,
                          acc[jt][1] * inv * xe[jt].y);
        p.y = cvt_pk_bf16(acc[jt][2] * inv * xe[jt].z,
                          acc[jt][3] * inv * xe[jt].w);
        *(uint2*)&Xs[bl][jt * 16 + hi * 4] = p;
      }
    }
    #pragma unroll
    for (int kf = 0; kf < 3; ++kf)
      Bf[kf] = *(const bf16x8*)&Xs[bl][kf * 32 + hi * 8];
  };

  auto phi = [&]() -> double {
    float sum = 0.f;
    #pragma unroll
    for (int u = 0; u < 24; ++u) sum += bf2f(Xs[bl][hi * 24 + u]);
    sum += __shfl_xor(sum, 16);
    sum += __shfl_xor(sum, 32);
    return Mref + (double)__logf(sum);
  };

  // prologue: fill 3 buffers (every chunk has >= 8 steps)
  load(s_init + 1, e0b, m0);
  load(s_init + 2, e1b, m1);
  load(s_init + 3, e2b, m2);

  double phiA = 0.0;   // c == 0: Phi before chunk is 0 by construction
  int s = s_init + 1;
  for (; s + 2 <= s_end; s += 3) {
    step(s,     e0b, m0); if (s     == s_A) phiA = phi();
    step(s + 1, e1b, m1); if (s + 1 == s_A) phiA = phi();
    step(s + 2, e2b, m2); if (s + 2 == s_A) phiA = phi();
  }
  // tails (c==0: 8=2*3+2; c==1: 16=5*3+1; s_A is never in a tail position)
  if (s <= s_end) { step(s, e0b, m0); ++s; }
  if (s <= s_end) { step(s, e1b, m1); ++s; }
  const double phiB = phi();

  if (hi == 0) pden[c * B + b] = (float)(phiB - phiA);

  // ---- fused numerator: gold-path terms for t in [c*CLEN, c*CLEN+CLEN) ----
  const int t0 = c * CLEN;
  float nacc = 0.f, mcnt = 0.f;
  #pragma unroll
  for (int k = 0; k < CLEN / 4; ++k) {
    const int t  = t0 + 4 * k + hi;
    const int mt = mb[t];
    mcnt += (float)mt;
    if (t < T - 1) {
      const int tg  = tgb[t];
      const int tg1 = tgb[t + 1];
      nacc = fmaf(trans[tg * K + tg1], (float)mb[t + 1], nacc);
      nacc = fmaf(ib[(size_t)t * K + tg], (float)mt, nacc);
    }
  }
  nacc += __shfl_xor(nacc, 16); nacc += __shfl_xor(nacc, 32);
  mcnt += __shfl_xor(mcnt, 16); mcnt += __shfl_xor(mcnt, 32);
  if (hi == 0) {
    pnum[c * B + b] = nacc;
    pcnt[c * B + b] = mcnt;
  }
}

// ---------------- final reduce: last-tag gather + sum ----------------
__global__ __launch_bounds__(128) void crf_reduce(
    const float* __restrict__ inp, const int* __restrict__ tags,
    const int* __restrict__ mask,
    const float* __restrict__ pden, const float* __restrict__ pnum,
    const float* __restrict__ pcnt, float* __restrict__ out, int T)
{
  const int b = threadIdx.x;   // 128 = B
  float den = 0.f, num = 0.f, cnt = 0.f;
  for (int c = 0; c < CHUNKS; ++c) {
    den += pden[c * B + b];
    num += pnum[c * B + b];
    cnt += pcnt[c * B + b];
  }
  const int last_idx = (int)cnt - 1;
  float last_sc = 0.f;
  if (last_idx >= 0) {
    const int lt = tags[(size_t)b * T + last_idx];
    last_sc = inp[((size_t)b * T + (T - 1)) * K + lt]
            * (float)mask[(size_t)b * T + T - 1];
  }
  __shared__ float red[128];
  red[b] = num + last_sc - den;
  __syncthreads();
  #pragma unroll
  for (int s = 64; s > 0; s >>= 1) {
    if (b < s) red[b] += red[b + s];
    __syncthreads();
  }
  if (b == 0) out[0] = red[0];
}

extern "C" void kernel_launch(void* const* d_in, const int* in_sizes, int n_in,
                              void* d_out, int out_size, void* d_ws, size_t ws_size,
                              hipStream_t stream)
{
  const float* inp   = (const float*)d_in[0];
  const int*   tags  = (const int*)  d_in[1];
  const int*   mask  = (const int*)  d_in[2];
  const float* trans = (const float*)d_in[3];
  float*       out   = (float*)d_out;

  const int BT = in_sizes[1];
  const int T  = BT / B;   // 2048

  float* pden = (float*)d_ws;            // [CHUNKS][B]
  float* pnum = pden + CHUNKS * B;       // [CHUNKS][B]
  float* pcnt = pnum + CHUNKS * B;       // [CHUNKS][B]

  dim3 grid(B / NB, CHUNKS);
  crf_fwd_chunk<<<grid, 64, 0, stream>>>(inp, tags, mask, trans,
                                         pden, pnum, pcnt, T);
  crf_reduce<<<1, 128, 0, stream>>>(inp, tags, mask, pden, pnum, pcnt, out, T);

  (void)n_in; (void)out_size; (void)ws_size;
}

// Round 12
// 43.941 us; speedup vs baseline: 1.7370x; 1.6930x over previous
//
#include <hip/hip_runtime.h>

// CRF log-likelihood, B=128, T=2048, K=96 on gfx950.
//
// Chunked-parallel forward algorithm (verified R3/R4/R5/R10/R11): logZ
// telescopes into per-chunk Phi differences; exp(trans) contracts normalized
// alpha at Hilbert rate ~0.36/step, so chunks warm up from a fabricated init
// WARM steps early. Chunk contribution = Phi(end) - Phi(after-warmup).
//
// Round 12: R11 killed the prefetch-pinning theory (VGPR stayed 136, dur
// unchanged) -> per-step latency is structural. Cut WORK instead, all with
// verified mechanics:
//   WARM 16->8  (boundary err ~12*0.36^8*128*128 ~ 55 << 2.65e4 threshold)
//   CLEN 8->16  (CHUNKS=128; chip-steps 49152 -> 24504, at 4 waves/CU)
//   renorm every 2nd step (R5-verified loop shape: x2 pairs, 4 buffers)
// Step math, init, fused numerator, reduce: byte-identical to R10/R11.

constexpr int K      = 96;
constexpr int NB     = 16;   // batches per wave (MFMA N dim)
constexpr int CHUNKS = 128;
constexpr int CLEN   = 16;   // accumulated steps per chunk
constexpr int WARM   = 8;    // warm-up steps (clamped at t=0)
constexpr int B      = 128;

typedef __attribute__((ext_vector_type(8))) short bf16x8;
typedef __attribute__((ext_vector_type(4))) float f32x4;

__device__ __forceinline__ unsigned short f2bf(float f) {
  unsigned int b = __float_as_uint(f);
  return (unsigned short)((b + 0x7fff + ((b >> 16) & 1)) >> 16);  // RNE
}
__device__ __forceinline__ float bf2f(unsigned short h) {
  return __uint_as_float(((unsigned int)h) << 16);
}
__device__ __forceinline__ unsigned int cvt_pk_bf16(float lo, float hi) {
  unsigned int r;
  asm volatile("v_cvt_pk_bf16_f32 %0, %1, %2" : "=v"(r) : "v"(lo), "v"(hi));
  return r;
}
__device__ __forceinline__ float lane_bcast(int addr4, float v) {
  return __int_as_float(__builtin_amdgcn_ds_bpermute(addr4, __float_as_int(v)));
}

__global__ __launch_bounds__(64, 1) void crf_fwd_chunk(
    const float* __restrict__ inp,    // [B,T,K]
    const int*   __restrict__ tags,   // [B,T]
    const int*   __restrict__ mask,   // [B,T]
    const float* __restrict__ trans,  // [K,K]
    float* __restrict__ pden,         // [CHUNKS][B]
    float* __restrict__ pnum,         // [CHUNKS][B]
    float* __restrict__ pcnt,         // [CHUNKS][B]
    int T)
{
  const int l  = threadIdx.x;
  const int bl = l & 15;     // batch-in-group (= MFMA col)
  const int hi = l >> 4;
  const int g  = blockIdx.x;
  const int c  = blockIdx.y;
  const int b  = g * NB + bl;
  const int bcast = bl * 4;

  const int s_init = max(0, c * CLEN - WARM);
  const int s_A    = c * CLEN;
  const int s_end  = min(c * CLEN + CLEN, T - 1);

  __shared__ unsigned short Xs[NB][104];   // bf16 state, stride 104 shorts

  // A fragments: A[row=j][k=i] = exp(trans[i][j]); row=lane&15, k=(lane>>4)*8+e
  bf16x8 A[6][3];
  #pragma unroll
  for (int jt = 0; jt < 6; ++jt) {
    #pragma unroll
    for (int kf = 0; kf < 3; ++kf) {
      const int j = jt * 16 + bl;
      #pragma unroll
      for (int e = 0; e < 8; ++e) {
        const int i = kf * 32 + hi * 8 + e;
        A[jt][kf][e] = (short)f2bf(__expf(trans[i * K + j]));
      }
    }
  }

  const float* ib  = inp  + (size_t)b * T * K;
  const int*   mb  = mask + (size_t)b * T;
  const int*   tgb = tags + (size_t)b * T;

  // ---- init at s_init: x = exp(emit - emit[0]) (exact for s_init==0) ----
  {
    const float* i0 = ib + (size_t)s_init * K;
    float4 e0[6];
    #pragma unroll
    for (int jt = 0; jt < 6; ++jt) {
      float4 v = *(const float4*)(i0 + jt * 16 + hi * 4);
      v.x = __expf(v.x); v.y = __expf(v.y); v.z = __expf(v.z); v.w = __expf(v.w);
      e0[jt] = v;
    }
    const float r0  = lane_bcast(bcast, e0[0].x);
    const float inv = 1.0f / r0;
    #pragma unroll
    for (int jt = 0; jt < 6; ++jt) {
      uint2 p;
      p.x = cvt_pk_bf16(e0[jt].x * inv, e0[jt].y * inv);
      p.y = cvt_pk_bf16(e0[jt].z * inv, e0[jt].w * inv);
      *(uint2*)&Xs[bl][jt * 16 + hi * 4] = p;
    }
  }
  double Mref = (double)ib[(size_t)s_init * K];

  bf16x8 Bf[3];
  #pragma unroll
  for (int kf = 0; kf < 3; ++kf)
    Bf[kf] = *(const bf16x8*)&Xs[bl][kf * 32 + hi * 8];

  // 4 named buffers (R5-verified loop shape)
  float4 A0[6], A1[6], B0[6], B1[6];
  int    mA0 = 0, mA1 = 0, mB0 = 0, mB1 = 0;

  auto loadE = [&](int s, float4 (&e)[6], int& m) {
    if (s <= s_end) {
      #pragma unroll
      for (int jt = 0; jt < 6; ++jt)
        e[jt] = *(const float4*)(ib + (size_t)s * K + jt * 16 + hi * 4);
      m = mb[s];
    }
  };

  // one step; renorm only when flagged (Phi = Mref + log sum x is
  // scale-correct at any time; renorm-every-2 keeps x within fp32/bf16 range)
  auto dostep = [&](float4 (&ebuf)[6], int msl, bool renorm) {
    f32x4 acc[6];
    #pragma unroll
    for (int jt = 0; jt < 6; ++jt) {
      f32x4 a = {0.f, 0.f, 0.f, 0.f};
      a = __builtin_amdgcn_mfma_f32_16x16x32_bf16(A[jt][0], Bf[0], a, 0, 0, 0);
      a = __builtin_amdgcn_mfma_f32_16x16x32_bf16(A[jt][1], Bf[1], a, 0, 0, 0);
      a = __builtin_amdgcn_mfma_f32_16x16x32_bf16(A[jt][2], Bf[2], a, 0, 0, 0);
      acc[jt] = a;
    }
    const bool mm = msl != 0;
    float inv = 1.0f;
    if (renorm) {
      const float r = lane_bcast(bcast, acc[0][0]);   // C[0][b]
      inv = 1.0f / r;
      if (mm) Mref += (double)__logf(r);
    }
    if (mm) {   // masked steps keep old x
      #pragma unroll
      for (int jt = 0; jt < 6; ++jt) {
        const float4 e4 = ebuf[jt];
        uint2 p;
        p.x = cvt_pk_bf16(acc[jt][0] * inv * __expf(e4.x),
                          acc[jt][1] * inv * __expf(e4.y));
        p.y = cvt_pk_bf16(acc[jt][2] * inv * __expf(e4.z),
                          acc[jt][3] * inv * __expf(e4.w));
        *(uint2*)&Xs[bl][jt * 16 + hi * 4] = p;
      }
    }
    #pragma unroll
    for (int kf = 0; kf < 3; ++kf)
      Bf[kf] = *(const bf16x8*)&Xs[bl][kf * 32 + hi * 8];
  };

  auto phi = [&]() -> double {
    float sum = 0.f;
    #pragma unroll
    for (int u = 0; u < 24; ++u) sum += bf2f(Xs[bl][hi * 24 + u]);
    sum += __shfl_xor(sum, 16);
    sum += __shfl_xor(sum, 32);
    return Mref + (double)__logf(sum);
  };

  loadE(s_init + 1, A0, mA0); loadE(s_init + 2, A1, mA1);
  loadE(s_init + 3, B0, mB0); loadE(s_init + 4, B1, mB1);

  double phiA = 0.0;   // c==0: Phi before chunk is 0 by construction
  int s = s_init + 1;
  while (s + 3 <= s_end) {
    dostep(A0, mA0, false);
    dostep(A1, mA1, true);
    if (s + 1 == s_A) phiA = phi();
    loadE(s + 4, A0, mA0); loadE(s + 5, A1, mA1);
    dostep(B0, mB0, false);
    dostep(B1, mB1, true);
    if (s + 3 == s_A) phiA = phi();
    loadE(s + 6, B0, mB0); loadE(s + 7, B1, mB1);
    s += 4;
  }
  // tails: remaining r = s_end-s+1 in {0,2,3} for this geometry (r=1 guarded)
  if (s + 1 <= s_end) {
    dostep(A0, mA0, false);
    dostep(A1, mA1, true);
    if (s + 1 == s_A) phiA = phi();
    s += 2;
    if (s <= s_end) { dostep(B0, mB0, true); ++s; }
  } else if (s <= s_end) {
    dostep(A0, mA0, true);
    ++s;
  }
  const double phiB = phi();

  if (hi == 0) pden[c * B + b] = (float)(phiB - phiA);

  // ---- fused numerator: gold-path terms for t in [c*CLEN, c*CLEN+CLEN) ----
  const int t0 = c * CLEN;
  float nacc = 0.f, mcnt = 0.f;
  #pragma unroll
  for (int k = 0; k < CLEN / 4; ++k) {
    const int t  = t0 + 4 * k + hi;
    const int mt = mb[t];
    mcnt += (float)mt;
    if (t < T - 1) {
      const int tg  = tgb[t];
      const int tg1 = tgb[t + 1];
      nacc = fmaf(trans[tg * K + tg1], (float)mb[t + 1], nacc);
      nacc = fmaf(ib[(size_t)t * K + tg], (float)mt, nacc);
    }
  }
  nacc += __shfl_xor(nacc, 16); nacc += __shfl_xor(nacc, 32);
  mcnt += __shfl_xor(mcnt, 16); mcnt += __shfl_xor(mcnt, 32);
  if (hi == 0) {
    pnum[c * B + b] = nacc;
    pcnt[c * B + b] = mcnt;
  }
}

// ---------------- final reduce: last-tag gather + sum ----------------
__global__ __launch_bounds__(128) void crf_reduce(
    const float* __restrict__ inp, const int* __restrict__ tags,
    const int* __restrict__ mask,
    const float* __restrict__ pden, const float* __restrict__ pnum,
    const float* __restrict__ pcnt, float* __restrict__ out, int T)
{
  const int b = threadIdx.x;   // 128 = B
  float den = 0.f, num = 0.f, cnt = 0.f;
  for (int c = 0; c < CHUNKS; ++c) {
    den += pden[c * B + b];
    num += pnum[c * B + b];
    cnt += pcnt[c * B + b];
  }
  const int last_idx = (int)cnt - 1;
  float last_sc = 0.f;
  if (last_idx >= 0) {
    const int lt = tags[(size_t)b * T + last_idx];
    last_sc = inp[((size_t)b * T + (T - 1)) * K + lt]
            * (float)mask[(size_t)b * T + T - 1];
  }
  __shared__ float red[128];
  red[b] = num + last_sc - den;
  __syncthreads();
  #pragma unroll
  for (int s = 64; s > 0; s >>= 1) {
    if (b < s) red[b] += red[b + s];
    __syncthreads();
  }
  if (b == 0) out[0] = red[0];
}

extern "C" void kernel_launch(void* const* d_in, const int* in_sizes, int n_in,
                              void* d_out, int out_size, void* d_ws, size_t ws_size,
                              hipStream_t stream)
{
  const float* inp   = (const float*)d_in[0];
  const int*   tags  = (const int*)  d_in[1];
  const int*   mask  = (const int*)  d_in[2];
  const float* trans = (const float*)d_in[3];
  float*       out   = (float*)d_out;

  const int BT = in_sizes[1];
  const int T  = BT / B;   // 2048

  float* pden = (float*)d_ws;            // [CHUNKS][B]
  float* pnum = pden + CHUNKS * B;       // [CHUNKS][B]
  float* pcnt = pnum + CHUNKS * B;       // [CHUNKS][B]

  dim3 grid(B / NB, CHUNKS);
  crf_fwd_chunk<<<grid, 64, 0, stream>>>(inp, tags, mask, trans,
                                         pden, pnum, pcnt, T);
  crf_reduce<<<1, 128, 0, stream>>>(inp, tags, mask, pden, pnum, pcnt, out, T);

  (void)n_in; (void)out_size; (void)ws_size;
}